// Round 5
// baseline (608.416 us; speedup 1.0000x reference)
//
#include <hip/hip_runtime.h>
#include <stdint.h>

#define S_LEN 2048
#define NH    16
#define NB    4
#define DH    64
#define DMODEL 1024

using bf16x8 = __attribute__((ext_vector_type(8))) __bf16;
using f32x4  = __attribute__((ext_vector_type(4))) float;
using us8    = __attribute__((ext_vector_type(8))) unsigned short;

__device__ __forceinline__ unsigned short f2bf_rne(float f) {
    unsigned u = __builtin_bit_cast(unsigned, f);
    return (unsigned short)((u + 0x7FFFu + ((u >> 16) & 1u)) >> 16);
}

__device__ __forceinline__ bf16x8 ld_bf8(const unsigned short* p) {
    return __builtin_bit_cast(bf16x8, *(const us8*)p);
}

__device__ __forceinline__ f32x4 mfma16(bf16x8 a, bf16x8 b, f32x4 c) {
    return __builtin_amdgcn_mfma_f32_16x16x32_bf16(a, b, c, 0, 0, 0);
}

__device__ __forceinline__ float fast_exp2(float x) {
#if __has_builtin(__builtin_amdgcn_exp2f)
    return __builtin_amdgcn_exp2f(x);
#else
    return __expf(x * 0.69314718056f);
#endif
}

typedef __attribute__((address_space(1))) void* gp1_t;
typedef __attribute__((address_space(3))) void* lp3_t;

__device__ __forceinline__ void gload_lds16(const void* g, void* l) {
    __builtin_amdgcn_global_load_lds((gp1_t)(const_cast<void*>(g)), (lp3_t)l, 16, 0, 0);
}

// wait own staging loads + block barrier (memory clobber = compiler fence)
#define VM_BARRIER() asm volatile("s_waitcnt vmcnt(0)\n\ts_barrier" ::: "memory")

// ---------------- fp32 -> bf16 convert ----------------
__global__ void cvt_bf16(const float* __restrict__ in, unsigned short* __restrict__ out, int n4) {
    int i = blockIdx.x * 256 + threadIdx.x;
    if (i < n4) {
        float4 v = ((const float4*)in)[i];
        ushort4 o;
        o.x = f2bf_rne(v.x); o.y = f2bf_rne(v.y);
        o.z = f2bf_rne(v.z); o.w = f2bf_rne(v.w);
        ((ushort4*)out)[i] = o;
    }
}

// ---------------- 256-wide bf16 MFMA GEMM (K = 1024), NT layout ----------------
// BM=256 x BN(256|128), BK=64, 8 waves (512 thr), double-buffered LDS,
// 2-phase: STAGE(next buf) BEFORE compute(cur), ONE vmcnt(0)+barrier per K-tile.
// LDS: linear dest for global_load_lds; global source pre-XOR-swizzled per 16B
// unit (slot ^= row&7) and the same XOR applied on ds_read -> 2-way max bank
// aliasing (free) instead of 8-way on the naive [row][BK] layout.
// XCD-chunked block swizzle (grid % 8 == 0 for both uses).
// EPI==0: QKV epilogue -> Qb (prescaled by 0.125*log2e), Kb [B,H,S,DH], Vt [B,H,DH,S]
// EPI==1: fp32 out + bias
template <int EPI, int BN>
__global__ __launch_bounds__(512, 2) void gemm256(
    const unsigned short* __restrict__ A,
    const unsigned short* __restrict__ W,
    const float* __restrict__ bias,
    float* __restrict__ outF,
    unsigned short* __restrict__ Qb,
    unsigned short* __restrict__ Kb,
    unsigned short* __restrict__ Vt,
    int nTilesN)
{
    constexpr int BM = 256, BK = 64;
    constexpr int WGN = BN / 64;          // waves along N: 4 (BN=256) or 2 (BN=128)
    constexpr int WM  = BM / (8 / WGN);   // wave M-tile: 128 or 64
    constexpr int MI  = WM / 16;          // 8 or 4
    constexpr int NJ  = 4;                // wave N-tile fixed 64
    constexpr int AI  = (BM * BK / 8) / 512;  // staging instrs/thread for A: 4
    constexpr int BI  = (BN * BK / 8) / 512;  // 4 or 2

    __shared__ __align__(16) unsigned short As[2][BM * BK];
    __shared__ __align__(16) unsigned short Bs[2][BN * BK];

    // XCD-chunked swizzle (bijective: gridDim.x % 8 == 0)
    const int nwg = gridDim.x;
    const int swz = (blockIdx.x & 7) * (nwg >> 3) + (blockIdx.x >> 3);
    const int bm = swz / nTilesN;
    const int bn = swz % nTilesN;
    const int tileM = bm * BM, tileN = bn * BN;

    const int tid = threadIdx.x, lane = tid & 63, w = tid >> 6;
    const int m16 = lane & 15, quad = lane >> 4;
    const int wm = w / WGN, wn = w % WGN;

    f32x4 acc[MI][NJ] = {};

    // staging: 16B unit u = (i*8 + w)*64 + lane; row = u>>3, slot = u&7;
    // source slot pre-swizzled so linear LDS holds slot' = slot ^ (row&7)
    size_t aoff[AI], boff[BI];
#pragma unroll
    for (int i = 0; i < AI; i++) {
        const int u = (i * 8 + w) * 64 + lane;
        const int row = u >> 3, slot = u & 7;
        aoff[i] = (size_t)(tileM + row) * 1024 + (size_t)((slot ^ (row & 7)) * 8);
    }
#pragma unroll
    for (int i = 0; i < BI; i++) {
        const int u = (i * 8 + w) * 64 + lane;
        const int row = u >> 3, slot = u & 7;
        boff[i] = (size_t)(tileN + row) * 1024 + (size_t)((slot ^ (row & 7)) * 8);
    }

#define STAGE(buf, kk) do {                                               \
        _Pragma("unroll")                                                 \
        for (int i = 0; i < AI; i++)                                      \
            gload_lds16(A + aoff[i] + (kk), &As[buf][(i * 8 + w) * 512]); \
        _Pragma("unroll")                                                 \
        for (int i = 0; i < BI; i++)                                      \
            gload_lds16(W + boff[i] + (kk), &Bs[buf][(i * 8 + w) * 512]); \
    } while (0)

#define COMPUTE(buf) do {                                                          \
        _Pragma("unroll")                                                          \
        for (int ks = 0; ks < 2; ks++) {                                           \
            bf16x8 af[MI], bfv[NJ];                                                \
            _Pragma("unroll")                                                      \
            for (int i = 0; i < MI; i++) {                                         \
                const int R = wm * WM + i * 16 + m16;                              \
                af[i] = ld_bf8(&As[buf][(R * 8 + ((ks * 4 + quad) ^ (R & 7))) * 8]); \
            }                                                                      \
            _Pragma("unroll")                                                      \
            for (int j = 0; j < NJ; j++) {                                         \
                const int Rb = wn * 64 + j * 16 + m16;                             \
                bfv[j] = ld_bf8(&Bs[buf][(Rb * 8 + ((ks * 4 + quad) ^ (Rb & 7))) * 8]); \
            }                                                                      \
            _Pragma("unroll")                                                      \
            for (int i = 0; i < MI; i++)                                           \
                _Pragma("unroll")                                                  \
                for (int j = 0; j < NJ; j++)                                       \
                    acc[i][j] = mfma16(af[i], bfv[j], acc[i][j]);                  \
        }                                                                          \
    } while (0)

    STAGE(0, 0);
    VM_BARRIER();
    for (int kk = 0; kk < 1024; kk += 128) {
        if (kk + 64 < 1024) STAGE(1, kk + 64);
        COMPUTE(0);
        VM_BARRIER();
        if (kk + 128 < 1024) STAGE(0, kk + 128);
        COMPUTE(1);
        VM_BARRIER();
    }
#undef STAGE
#undef COMPUTE

    // epilogue: C/D layout col = lane&15, row = quad*4 + reg
#pragma unroll
    for (int i = 0; i < MI; i++) {
        const int mrow = tileM + wm * WM + i * 16 + quad * 4;
#pragma unroll
        for (int j = 0; j < NJ; j++) {
            const int nb0 = tileN + wn * 64 + j * 16;
            const int n = nb0 + m16;
            const float bv = bias[n];
            if (EPI == 0) {
                const int hh = nb0 / 192, rem = nb0 % 192;
                const int t = rem / 64, dbase = rem % 64;
                const int d = dbase + m16;
#pragma unroll
                for (int r = 0; r < 4; r++) {
                    float val = acc[i][j][r] + bv;
                    const int m = mrow + r;
                    const int b_ = m >> 11, s_ = m & 2047;
                    const size_t bh = (size_t)b_ * NH + hh;
                    if (t == 0)
                        Qb[(bh * S_LEN + s_) * DH + d] = f2bf_rne(val * 0.18033688f); // 0.125*log2e
                    else if (t == 1)
                        Kb[(bh * S_LEN + s_) * DH + d] = f2bf_rne(val);
                    else
                        Vt[(bh * DH + d) * S_LEN + s_] = f2bf_rne(val);  // transposed V
                }
            } else {
#pragma unroll
                for (int r = 0; r < 4; r++) {
                    const int m = mrow + r;
                    outF[(size_t)m * DMODEL + n] = acc[i][j][r] + bv;
                }
            }
        }
    }
}

// ---------------- fused attention ----------------
// block = (b, h, 128 q-rows); 4 waves, each handling 32 q-rows (2 x 16-row frags)
// K-chunk = 128 keys staged in LDS (XOR-swizzled), V likewise from Vt [d][s].
// QK uses mfma(K,Q) so each lane holds 4 k-consecutive logits.
// ALIBI depth-1 PREFETCH (R4 verified: attn 226->184 us, no spill).
__global__ __launch_bounds__(256, 4) void attn(const unsigned short* __restrict__ Qb,
                                               const unsigned short* __restrict__ Kb,
                                               const unsigned short* __restrict__ Vt,
                                               const float* __restrict__ alibi,
                                               unsigned short* __restrict__ ob) {
    const int blk = blockIdx.x;
    // XCD swizzle: 4 batch-siblings (same alibi strip) at blkIdx stride 8 -> same XCD L2
    const int xcd = blk & 7;
    const int b_  = (blk >> 3) & 3;
    const int hq  = xcd * 32 + (blk >> 5);     // 0..255
    const int hh  = hq >> 4, qt = hq & 15;
    const int tid = threadIdx.x, lane = tid & 63, w = tid >> 6;
    const int m16 = lane & 15, quad = lane >> 4;
    const int q0 = qt * 128;
    const size_t bh = (size_t)b_ * NH + hh;

    const unsigned short* Qp = Qb + (bh * S_LEN) * DH;
    const unsigned short* Kp = Kb + bh * S_LEN * DH;
    const unsigned short* Vp = Vt + bh * DH * S_LEN;

    __shared__ __align__(16) unsigned short Ks[128 * 64];   // [key][d], d-swizzled
    __shared__ __align__(16) unsigned short Vs[64 * 128];   // [d][key], key-swizzled
    __shared__ __align__(16) unsigned int   Pl[4][16 * 20]; // per-wave, stride 20 dwords

    // Q fragments (Q pre-scaled by 0.125*log2e)
    bf16x8 qfrag[2][2];
#pragma unroll
    for (int qf = 0; qf < 2; qf++) {
        const unsigned short* qp = Qp + (size_t)(q0 + w * 32 + qf * 16 + m16) * DH + quad * 8;
        qfrag[qf][0] = ld_bf8(qp);
        qfrag[qf][1] = ld_bf8(qp + 32);
    }
    const float* Apq[2];
#pragma unroll
    for (int qf = 0; qf < 2; qf++)
        Apq[qf] = alibi + ((size_t)hh * S_LEN + q0 + w * 32 + qf * 16 + m16) * S_LEN + quad * 4;

    // staging offsets (global-side XOR swizzle; LDS side is lane-contiguous)
    int offk[4], offv[4];
#pragma unroll
    for (int t = 0; t < 4; t++) {
        const int ck = (w * 4 + t) * 64 + lane;
        const int rk = ck >> 3;
        offk[t] = rk * DH + ((ck & 7) ^ (rk & 7)) * 8;
        const int cv = ck;
        const int dv = cv >> 4;
        offv[t] = dv * S_LEN + ((cv & 15) ^ (dv & 15)) * 8;
    }

    const bf16x8 onesf = __builtin_bit_cast(bf16x8, (us8)(0x3F80u));
    f32x4 oacc[2][4] = {};
    f32x4 ssum[2] = {};
    unsigned int* plw = &Pl[w][0];
    const int sA = m16 & 7;

    // prologue prefetch for step (kc=0, qf=0, kc2=0)
    float4 alc0 = *(const float4*)(Apq[0]);
    float4 alc1 = *(const float4*)(Apq[0] + 16);

    for (int kc = 0; kc < S_LEN; kc += 128) {
        __syncthreads();  // previous compute done before overwrite
#pragma unroll
        for (int t = 0; t < 4; t++)
            gload_lds16(Kp + (size_t)kc * DH + offk[t], &Ks[(w * 4 + t) * 512]);
#pragma unroll
        for (int t = 0; t < 4; t++)
            gload_lds16(Vp + kc + offv[t], &Vs[(w * 4 + t) * 512]);
        __syncthreads();  // staging visible to all waves

#pragma unroll
        for (int qf = 0; qf < 2; qf++) {
            const bf16x8 qa = qfrag[qf][0], qb2 = qfrag[qf][1];
#pragma unroll
            for (int kc2 = 0; kc2 < 4; kc2++) {
                // issue NEXT step's alibi prefetch (step chain: kc2 -> qf -> kc;
                // last chunk wraps in-bounds, value never consumed)
                const float* nptr = (kc2 < 3) ? (Apq[qf] + kc + (kc2 + 1) * 32)
                                  : (qf == 0) ? (Apq[1] + kc)
                                              : (Apq[0] + ((kc + 128) & (S_LEN - 1)));
                const float4 aln0 = *(const float4*)(nptr);
                const float4 aln1 = *(const float4*)(nptr + 16);

                f32x4 sc[2];
                __builtin_amdgcn_s_setprio(1);
#pragma unroll
                for (int t = 0; t < 2; t++) {
                    const int krow = (kc2 * 2 + t) * 16 + m16;
                    f32x4 z = {};
                    z = mfma16(ld_bf8(&Ks[krow * DH + (quad ^ sA) * 8]), qa, z);
                    z = mfma16(ld_bf8(&Ks[krow * DH + ((quad + 4) ^ sA) * 8]), qb2, z);
                    sc[t] = z;
                }
                __builtin_amdgcn_s_setprio(0);
                // alibi + exp2 + truncate-pack; lane holds keys kc+kc2*32+t*16+quad*4+r
#pragma unroll
                for (int t = 0; t < 2; t++) {
                    const float4 av = (t == 0) ? alc0 : alc1;
                    float p0 = fast_exp2(__builtin_fmaf(av.x, 1.44269504f, sc[t][0]));
                    float p1 = fast_exp2(__builtin_fmaf(av.y, 1.44269504f, sc[t][1]));
                    float p2 = fast_exp2(__builtin_fmaf(av.z, 1.44269504f, sc[t][2]));
                    float p3 = fast_exp2(__builtin_fmaf(av.w, 1.44269504f, sc[t][3]));
                    uint2 pk;
                    pk.x = (__builtin_bit_cast(unsigned, p0) >> 16) |
                           (__builtin_bit_cast(unsigned, p1) & 0xFFFF0000u);
                    pk.y = (__builtin_bit_cast(unsigned, p2) >> 16) |
                           (__builtin_bit_cast(unsigned, p3) & 0xFFFF0000u);
                    *(uint2*)&plw[m16 * 20 + t * 8 + quad * 2] = pk;
                }
                // P (A-layout) read-back; PV + ones-rowsum (same-wave DS ordering)
                const bf16x8 pf = ld_bf8((const unsigned short*)&plw[m16 * 20 + quad * 4]);
                __builtin_amdgcn_s_setprio(1);
                ssum[qf] = mfma16(pf, onesf, ssum[qf]);
#pragma unroll
                for (int db = 0; db < 4; db++) {
                    const int vrow = db * 16 + m16;
                    const bf16x8 vf = ld_bf8(&Vs[vrow * 128 + ((kc2 * 4 + quad) ^ m16) * 8]);
                    oacc[qf][db] = mfma16(pf, vf, oacc[qf][db]);
                }
                __builtin_amdgcn_s_setprio(0);

                alc0 = aln0;  // rotate pipeline (register rename, free)
                alc1 = aln1;
            }
        }
    }

    // normalize + store o as bf16 [B,S,D]; ssum rows == oacc rows (both C-layout)
#pragma unroll
    for (int qf = 0; qf < 2; qf++) {
        f32x4 rinv;
#pragma unroll
        for (int r = 0; r < 4; r++) rinv[r] = 1.0f / ssum[qf][r];
#pragma unroll
        for (int db = 0; db < 4; db++)
#pragma unroll
            for (int r = 0; r < 4; r++) {
                const int q = q0 + w * 32 + qf * 16 + quad * 4 + r;
                ob[((size_t)b_ * S_LEN + q) * DMODEL + hh * DH + db * 16 + m16] =
                    f2bf_rne(oacc[qf][db][r] * rinv[r]);
            }
    }
}

extern "C" void kernel_launch(void* const* d_in, const int* in_sizes, int n_in,
                              void* d_out, int out_size, void* d_ws, size_t ws_size,
                              hipStream_t stream) {
    (void)in_sizes; (void)n_in; (void)out_size; (void)ws_size;
    const float* x      = (const float*)d_in[0];
    const float* alibi  = (const float*)d_in[1];
    const float* w_qkv  = (const float*)d_in[2];
    const float* b_qkv  = (const float*)d_in[3];
    const float* w_o    = (const float*)d_in[4];
    const float* b_o    = (const float*)d_in[5];
    float* out = (float*)d_out;

    char* ws = (char*)d_ws;
    unsigned short* xb    = (unsigned short*)(ws);              // 16.78 MB
    unsigned short* wqkvb = (unsigned short*)(ws + 16777216);   //  6.29 MB
    unsigned short* wob   = (unsigned short*)(ws + 23068672);   //  2.10 MB
    unsigned short* Qb    = (unsigned short*)(ws + 25165824);   // 16.78 MB
    unsigned short* Kb    = (unsigned short*)(ws + 41943040);   // 16.78 MB
    unsigned short* Vt    = (unsigned short*)(ws + 58720256);   // 16.78 MB
    unsigned short* ob    = (unsigned short*)(ws + 75497472);   // 16.78 MB (total ~92 MB)

    cvt_bf16<<<8192, 256, 0, stream>>>(x, xb, 8388608 / 4);
    cvt_bf16<<<3072, 256, 0, stream>>>(w_qkv, wqkvb, 3145728 / 4);
    cvt_bf16<<<1024, 256, 0, stream>>>(w_o, wob, 1048576 / 4);

    // QKV: M=8192, N=3072 -> 32 x 12 = 384 blocks (384 % 8 == 0)
    gemm256<0, 256><<<384, 512, 0, stream>>>(xb, wqkvb, b_qkv, nullptr, Qb, Kb, Vt, 12);
    attn<<<1024, 256, 0, stream>>>(Qb, Kb, Vt, alibi, ob);
    // out-proj: M=8192, N=1024 -> 32 x 8 = 256 blocks (256 % 8 == 0)
    gemm256<1, 128><<<256, 512, 0, stream>>>(ob, wob, b_o, out, nullptr, nullptr, nullptr, 8);
}

// Round 6
// 606.574 us; speedup vs baseline: 1.0030x; 1.0030x over previous
//
#include <hip/hip_runtime.h>
#include <stdint.h>

#define S_LEN 2048
#define NH    16
#define NB    4
#define DH    64
#define DMODEL 1024

using bf16x8 = __attribute__((ext_vector_type(8))) __bf16;
using f32x4  = __attribute__((ext_vector_type(4))) float;
using us8    = __attribute__((ext_vector_type(8))) unsigned short;

__device__ __forceinline__ unsigned short f2bf_rne(float f) {
    unsigned u = __builtin_bit_cast(unsigned, f);
    return (unsigned short)((u + 0x7FFFu + ((u >> 16) & 1u)) >> 16);
}

__device__ __forceinline__ bf16x8 ld_bf8(const unsigned short* p) {
    return __builtin_bit_cast(bf16x8, *(const us8*)p);
}

__device__ __forceinline__ f32x4 mfma16(bf16x8 a, bf16x8 b, f32x4 c) {
    return __builtin_amdgcn_mfma_f32_16x16x32_bf16(a, b, c, 0, 0, 0);
}

__device__ __forceinline__ float fast_exp2(float x) {
#if __has_builtin(__builtin_amdgcn_exp2f)
    return __builtin_amdgcn_exp2f(x);
#else
    return __expf(x * 0.69314718056f);
#endif
}

typedef __attribute__((address_space(1))) void* gp1_t;
typedef __attribute__((address_space(3))) void* lp3_t;

__device__ __forceinline__ void gload_lds16(const void* g, void* l) {
    __builtin_amdgcn_global_load_lds((gp1_t)(const_cast<void*>(g)), (lp3_t)l, 16, 0, 0);
}

// counted-vmcnt pipeline primitives (T4): NEVER drain vmcnt to 0 in the main
// loop — wait only for the buffer about to be computed, leaving the prefetch
// in flight across the barrier. "memory" clobber = compiler fence.
#define GBAR()  asm volatile("s_barrier" ::: "memory")
#define WAIT6() asm volatile("s_waitcnt vmcnt(6)" ::: "memory")
#define WAIT0() asm volatile("s_waitcnt vmcnt(0)" ::: "memory")

// ---------------- fp32 -> bf16 convert ----------------
__global__ void cvt_bf16(const float* __restrict__ in, unsigned short* __restrict__ out, int n4) {
    int i = blockIdx.x * 256 + threadIdx.x;
    if (i < n4) {
        float4 v = ((const float4*)in)[i];
        ushort4 o;
        o.x = f2bf_rne(v.x); o.y = f2bf_rne(v.y);
        o.z = f2bf_rne(v.z); o.w = f2bf_rne(v.w);
        ((ushort4*)out)[i] = o;
    }
}

// ---------------- 256x128x64 bf16 MFMA GEMM (K = 1024), NT layout ----------------
// 8 waves (512 thr) as 4M x 2N, wave tile 64x64, double-buffered LDS (96 KiB),
// counted-vmcnt pipeline: prefetch stays in flight across barriers (wait
// vmcnt(6) = next tile's 6 loads), tile t+1 gets a full compute phase of
// latency hiding. R5's drain-0 VM_BARRIER exposed full HBM latency per tile
// and measured == serial structure.
// LDS: linear dest for global_load_lds; global source pre-XOR-swizzled per
// 16B unit (slot ^= row&7), same XOR on ds_read -> 2-way max bank aliasing.
// XCD-chunked block swizzle (grid % 8 == 0 for both uses).
// EPI==0: QKV epilogue -> Qb (prescaled by 0.125*log2e), Kb [B,H,S,DH], Vt [B,H,DH,S]
// EPI==1: fp32 out + bias
template <int EPI>
__global__ __launch_bounds__(512, 2) void gemm256(
    const unsigned short* __restrict__ A,
    const unsigned short* __restrict__ W,
    const float* __restrict__ bias,
    float* __restrict__ outF,
    unsigned short* __restrict__ Qb,
    unsigned short* __restrict__ Kb,
    unsigned short* __restrict__ Vt,
    int nTilesN)
{
    constexpr int BM = 256, BN = 128, BK = 64;
    constexpr int MI = 4, NJ = 4;             // wave tile 64x64
    constexpr int AI = (BM * BK / 8) / 512;   // 4 staging instrs/thread for A
    constexpr int BI = (BN * BK / 8) / 512;   // 2 for B  -> L = 6 in flight

    __shared__ __align__(16) unsigned short As[2][BM * BK];
    __shared__ __align__(16) unsigned short Bs[2][BN * BK];

    // XCD-chunked swizzle (bijective: gridDim.x % 8 == 0)
    const int nwg = gridDim.x;
    const int swz = (blockIdx.x & 7) * (nwg >> 3) + (blockIdx.x >> 3);
    const int bm = swz / nTilesN;
    const int bn = swz % nTilesN;
    const int tileM = bm * BM, tileN = bn * BN;

    const int tid = threadIdx.x, lane = tid & 63, w = tid >> 6;
    const int m16 = lane & 15, quad = lane >> 4;
    const int wm = w >> 1, wn = w & 1;

    f32x4 acc[MI][NJ] = {};

    // staging: 16B unit u = (i*8 + w)*64 + lane; row = u>>3, slot = u&7;
    // source slot pre-swizzled so linear LDS holds slot' = slot ^ (row&7)
    size_t aoff[AI], boff[BI];
#pragma unroll
    for (int i = 0; i < AI; i++) {
        const int u = (i * 8 + w) * 64 + lane;
        const int row = u >> 3, slot = u & 7;
        aoff[i] = (size_t)(tileM + row) * 1024 + (size_t)((slot ^ (row & 7)) * 8);
    }
#pragma unroll
    for (int i = 0; i < BI; i++) {
        const int u = (i * 8 + w) * 64 + lane;
        const int row = u >> 3, slot = u & 7;
        boff[i] = (size_t)(tileN + row) * 1024 + (size_t)((slot ^ (row & 7)) * 8);
    }

#define STAGE(buf, kk) do {                                               \
        _Pragma("unroll")                                                 \
        for (int i = 0; i < AI; i++)                                      \
            gload_lds16(A + aoff[i] + (kk), &As[buf][(i * 8 + w) * 512]); \
        _Pragma("unroll")                                                 \
        for (int i = 0; i < BI; i++)                                      \
            gload_lds16(W + boff[i] + (kk), &Bs[buf][(i * 8 + w) * 512]); \
    } while (0)

#define COMPUTE(buf) do {                                                          \
        _Pragma("unroll")                                                          \
        for (int ks = 0; ks < 2; ks++) {                                           \
            bf16x8 af[MI], bfv[NJ];                                                \
            _Pragma("unroll")                                                      \
            for (int i = 0; i < MI; i++) {                                         \
                const int R = wm * 64 + i * 16 + m16;                              \
                af[i] = ld_bf8(&As[buf][(R * 8 + ((ks * 4 + quad) ^ (R & 7))) * 8]); \
            }                                                                      \
            _Pragma("unroll")                                                      \
            for (int j = 0; j < NJ; j++) {                                         \
                const int Rb = wn * 64 + j * 16 + m16;                             \
                bfv[j] = ld_bf8(&Bs[buf][(Rb * 8 + ((ks * 4 + quad) ^ (Rb & 7))) * 8]); \
            }                                                                      \
            _Pragma("unroll")                                                      \
            for (int i = 0; i < MI; i++)                                           \
                _Pragma("unroll")                                                  \
                for (int j = 0; j < NJ; j++)                                       \
                    acc[i][j] = mfma16(af[i], bfv[j], acc[i][j]);                  \
        }                                                                          \
    } while (0)

    // prologue: tiles 0,1 in flight; wait tile0 only (tile1 stays flying)
    STAGE(0, 0);
    STAGE(1, 64);
    WAIT6();
    GBAR();

    for (int kk = 0; kk < 1024; kk += 128) {
        COMPUTE(0);                                   // tile kk (buf0 ready)
        GBAR();                                       // all waves done reading buf0
        if (kk + 128 < 1024) { STAGE(0, kk + 128); WAIT6(); }  // issue t+2, wait t+1
        else                 { WAIT0(); }             // tail: only t+1 in flight
        GBAR();                                       // t+1 (buf1) visible to all
        COMPUTE(1);                                   // tile kk+64
        if (kk + 128 < 1024) {
            GBAR();                                   // done reading buf1
            if (kk + 192 < 1024) { STAGE(1, kk + 192); WAIT6(); }
            else                 { WAIT0(); }
            GBAR();
        }
    }
#undef STAGE
#undef COMPUTE

    // epilogue: C/D layout col = lane&15, row = quad*4 + reg
#pragma unroll
    for (int i = 0; i < MI; i++) {
        const int mrow = tileM + wm * 64 + i * 16 + quad * 4;
#pragma unroll
        for (int j = 0; j < NJ; j++) {
            const int nb0 = tileN + wn * 64 + j * 16;
            const int n = nb0 + m16;
            const float bv = bias[n];
            if (EPI == 0) {
                const int hh = nb0 / 192, rem = nb0 % 192;
                const int t = rem / 64, dbase = rem % 64;
                const int d = dbase + m16;
#pragma unroll
                for (int r = 0; r < 4; r++) {
                    float val = acc[i][j][r] + bv;
                    const int m = mrow + r;
                    const int b_ = m >> 11, s_ = m & 2047;
                    const size_t bh = (size_t)b_ * NH + hh;
                    if (t == 0)
                        Qb[(bh * S_LEN + s_) * DH + d] = f2bf_rne(val * 0.18033688f); // 0.125*log2e
                    else if (t == 1)
                        Kb[(bh * S_LEN + s_) * DH + d] = f2bf_rne(val);
                    else
                        Vt[(bh * DH + d) * S_LEN + s_] = f2bf_rne(val);  // transposed V
                }
            } else {
#pragma unroll
                for (int r = 0; r < 4; r++) {
                    const int m = mrow + r;
                    outF[(size_t)m * DMODEL + n] = acc[i][j][r] + bv;
                }
            }
        }
    }
}

// ---------------- fused attention ----------------
// block = (b, h, 128 q-rows); 4 waves, each handling 32 q-rows (2 x 16-row frags)
// K-chunk = 128 keys staged in LDS (XOR-swizzled), V likewise from Vt [d][s].
// QK uses mfma(K,Q) so each lane holds 4 k-consecutive logits.
// ALIBI depth-1 PREFETCH (R4 verified: attn 226->184 us, no spill).
__global__ __launch_bounds__(256, 4) void attn(const unsigned short* __restrict__ Qb,
                                               const unsigned short* __restrict__ Kb,
                                               const unsigned short* __restrict__ Vt,
                                               const float* __restrict__ alibi,
                                               unsigned short* __restrict__ ob) {
    const int blk = blockIdx.x;
    // XCD swizzle: 4 batch-siblings (same alibi strip) at blkIdx stride 8 -> same XCD L2
    const int xcd = blk & 7;
    const int b_  = (blk >> 3) & 3;
    const int hq  = xcd * 32 + (blk >> 5);     // 0..255
    const int hh  = hq >> 4, qt = hq & 15;
    const int tid = threadIdx.x, lane = tid & 63, w = tid >> 6;
    const int m16 = lane & 15, quad = lane >> 4;
    const int q0 = qt * 128;
    const size_t bh = (size_t)b_ * NH + hh;

    const unsigned short* Qp = Qb + (bh * S_LEN) * DH;
    const unsigned short* Kp = Kb + bh * S_LEN * DH;
    const unsigned short* Vp = Vt + bh * DH * S_LEN;

    __shared__ __align__(16) unsigned short Ks[128 * 64];   // [key][d], d-swizzled
    __shared__ __align__(16) unsigned short Vs[64 * 128];   // [d][key], key-swizzled
    __shared__ __align__(16) unsigned int   Pl[4][16 * 20]; // per-wave, stride 20 dwords

    // Q fragments (Q pre-scaled by 0.125*log2e)
    bf16x8 qfrag[2][2];
#pragma unroll
    for (int qf = 0; qf < 2; qf++) {
        const unsigned short* qp = Qp + (size_t)(q0 + w * 32 + qf * 16 + m16) * DH + quad * 8;
        qfrag[qf][0] = ld_bf8(qp);
        qfrag[qf][1] = ld_bf8(qp + 32);
    }
    const float* Apq[2];
#pragma unroll
    for (int qf = 0; qf < 2; qf++)
        Apq[qf] = alibi + ((size_t)hh * S_LEN + q0 + w * 32 + qf * 16 + m16) * S_LEN + quad * 4;

    // staging offsets (global-side XOR swizzle; LDS side is lane-contiguous)
    int offk[4], offv[4];
#pragma unroll
    for (int t = 0; t < 4; t++) {
        const int ck = (w * 4 + t) * 64 + lane;
        const int rk = ck >> 3;
        offk[t] = rk * DH + ((ck & 7) ^ (rk & 7)) * 8;
        const int cv = ck;
        const int dv = cv >> 4;
        offv[t] = dv * S_LEN + ((cv & 15) ^ (dv & 15)) * 8;
    }

    const bf16x8 onesf = __builtin_bit_cast(bf16x8, (us8)(0x3F80u));
    f32x4 oacc[2][4] = {};
    f32x4 ssum[2] = {};
    unsigned int* plw = &Pl[w][0];
    const int sA = m16 & 7;

    // prologue prefetch for step (kc=0, qf=0, kc2=0)
    float4 alc0 = *(const float4*)(Apq[0]);
    float4 alc1 = *(const float4*)(Apq[0] + 16);

    for (int kc = 0; kc < S_LEN; kc += 128) {
        __syncthreads();  // previous compute done before overwrite
#pragma unroll
        for (int t = 0; t < 4; t++)
            gload_lds16(Kp + (size_t)kc * DH + offk[t], &Ks[(w * 4 + t) * 512]);
#pragma unroll
        for (int t = 0; t < 4; t++)
            gload_lds16(Vp + kc + offv[t], &Vs[(w * 4 + t) * 512]);
        __syncthreads();  // staging visible to all waves

#pragma unroll
        for (int qf = 0; qf < 2; qf++) {
            const bf16x8 qa = qfrag[qf][0], qb2 = qfrag[qf][1];
#pragma unroll
            for (int kc2 = 0; kc2 < 4; kc2++) {
                // issue NEXT step's alibi prefetch (step chain: kc2 -> qf -> kc;
                // last chunk wraps in-bounds, value never consumed)
                const float* nptr = (kc2 < 3) ? (Apq[qf] + kc + (kc2 + 1) * 32)
                                  : (qf == 0) ? (Apq[1] + kc)
                                              : (Apq[0] + ((kc + 128) & (S_LEN - 1)));
                const float4 aln0 = *(const float4*)(nptr);
                const float4 aln1 = *(const float4*)(nptr + 16);

                f32x4 sc[2];
                __builtin_amdgcn_s_setprio(1);
#pragma unroll
                for (int t = 0; t < 2; t++) {
                    const int krow = (kc2 * 2 + t) * 16 + m16;
                    f32x4 z = {};
                    z = mfma16(ld_bf8(&Ks[krow * DH + (quad ^ sA) * 8]), qa, z);
                    z = mfma16(ld_bf8(&Ks[krow * DH + ((quad + 4) ^ sA) * 8]), qb2, z);
                    sc[t] = z;
                }
                __builtin_amdgcn_s_setprio(0);
                // alibi + exp2 + truncate-pack; lane holds keys kc+kc2*32+t*16+quad*4+r
#pragma unroll
                for (int t = 0; t < 2; t++) {
                    const float4 av = (t == 0) ? alc0 : alc1;
                    float p0 = fast_exp2(__builtin_fmaf(av.x, 1.44269504f, sc[t][0]));
                    float p1 = fast_exp2(__builtin_fmaf(av.y, 1.44269504f, sc[t][1]));
                    float p2 = fast_exp2(__builtin_fmaf(av.z, 1.44269504f, sc[t][2]));
                    float p3 = fast_exp2(__builtin_fmaf(av.w, 1.44269504f, sc[t][3]));
                    uint2 pk;
                    pk.x = (__builtin_bit_cast(unsigned, p0) >> 16) |
                           (__builtin_bit_cast(unsigned, p1) & 0xFFFF0000u);
                    pk.y = (__builtin_bit_cast(unsigned, p2) >> 16) |
                           (__builtin_bit_cast(unsigned, p3) & 0xFFFF0000u);
                    *(uint2*)&plw[m16 * 20 + t * 8 + quad * 2] = pk;
                }
                // P (A-layout) read-back; PV + ones-rowsum (same-wave DS ordering)
                const bf16x8 pf = ld_bf8((const unsigned short*)&plw[m16 * 20 + quad * 4]);
                __builtin_amdgcn_s_setprio(1);
                ssum[qf] = mfma16(pf, onesf, ssum[qf]);
#pragma unroll
                for (int db = 0; db < 4; db++) {
                    const int vrow = db * 16 + m16;
                    const bf16x8 vf = ld_bf8(&Vs[vrow * 128 + ((kc2 * 4 + quad) ^ m16) * 8]);
                    oacc[qf][db] = mfma16(pf, vf, oacc[qf][db]);
                }
                __builtin_amdgcn_s_setprio(0);

                alc0 = aln0;  // rotate pipeline (register rename, free)
                alc1 = aln1;
            }
        }
    }

    // normalize + store o as bf16 [B,S,D]; ssum rows == oacc rows (both C-layout)
#pragma unroll
    for (int qf = 0; qf < 2; qf++) {
        f32x4 rinv;
#pragma unroll
        for (int r = 0; r < 4; r++) rinv[r] = 1.0f / ssum[qf][r];
#pragma unroll
        for (int db = 0; db < 4; db++)
#pragma unroll
            for (int r = 0; r < 4; r++) {
                const int q = q0 + w * 32 + qf * 16 + quad * 4 + r;
                ob[((size_t)b_ * S_LEN + q) * DMODEL + hh * DH + db * 16 + m16] =
                    f2bf_rne(oacc[qf][db][r] * rinv[r]);
            }
    }
}

extern "C" void kernel_launch(void* const* d_in, const int* in_sizes, int n_in,
                              void* d_out, int out_size, void* d_ws, size_t ws_size,
                              hipStream_t stream) {
    (void)in_sizes; (void)n_in; (void)out_size; (void)ws_size;
    const float* x      = (const float*)d_in[0];
    const float* alibi  = (const float*)d_in[1];
    const float* w_qkv  = (const float*)d_in[2];
    const float* b_qkv  = (const float*)d_in[3];
    const float* w_o    = (const float*)d_in[4];
    const float* b_o    = (const float*)d_in[5];
    float* out = (float*)d_out;

    char* ws = (char*)d_ws;
    unsigned short* xb    = (unsigned short*)(ws);              // 16.78 MB
    unsigned short* wqkvb = (unsigned short*)(ws + 16777216);   //  6.29 MB
    unsigned short* wob   = (unsigned short*)(ws + 23068672);   //  2.10 MB
    unsigned short* Qb    = (unsigned short*)(ws + 25165824);   // 16.78 MB
    unsigned short* Kb    = (unsigned short*)(ws + 41943040);   // 16.78 MB
    unsigned short* Vt    = (unsigned short*)(ws + 58720256);   // 16.78 MB
    unsigned short* ob    = (unsigned short*)(ws + 75497472);   // 16.78 MB (total ~92 MB)

    cvt_bf16<<<8192, 256, 0, stream>>>(x, xb, 8388608 / 4);
    cvt_bf16<<<3072, 256, 0, stream>>>(w_qkv, wqkvb, 3145728 / 4);
    cvt_bf16<<<1024, 256, 0, stream>>>(w_o, wob, 1048576 / 4);

    // QKV: M=8192 (32 tiles of 256), N=3072 (24 tiles of 128) -> 768 blocks (3.0/CU, %8==0)
    gemm256<0><<<768, 512, 0, stream>>>(xb, wqkvb, b_qkv, nullptr, Qb, Kb, Vt, 24);
    attn<<<1024, 256, 0, stream>>>(Qb, Kb, Vt, alibi, ob);
    // out-proj: M=8192, N=1024 (8 tiles of 128) -> 256 blocks (1.0/CU, %8==0)
    gemm256<1><<<256, 512, 0, stream>>>(ob, wob, b_o, out, nullptr, nullptr, nullptr, 8);
}